// Round 3
// baseline (835.675 us; speedup 1.0000x reference)
//
#include <hip/hip_runtime.h>

#define NE   8
#define DIN  4096
#define DOUT 4096
#define TOK  8192

// fast-path tile
#define BM 256
#define BN 256
#define BK 32
#define NT (DIN / BK)      // 128 K-steps
#define TSZ (BM * BK)      // 8192 bf16 elems per operand buffer

// legacy fallback tile
#define FBM 128
#define FBK 32
#define LDSK 40

typedef __attribute__((ext_vector_type(4))) float f32x4;
typedef __attribute__((ext_vector_type(8))) short bf16x8;
typedef __attribute__((ext_vector_type(2))) unsigned long long u64x2;

#define AS1 __attribute__((address_space(1)))
#define AS3 __attribute__((address_space(3)))

static __device__ __forceinline__ unsigned short f2bf(float f) {
  unsigned u = __builtin_bit_cast(unsigned, f);
  u += 0x7fffu + ((u >> 16) & 1u);   // RTNE
  return (unsigned short)(u >> 16);
}

static __device__ __forceinline__ unsigned long long pack4(f32x4 v) {
  return (unsigned long long)f2bf(v[0])
       | ((unsigned long long)f2bf(v[1]) << 16)
       | ((unsigned long long)f2bf(v[2]) << 32)
       | ((unsigned long long)f2bf(v[3]) << 48);
}

// ---------- fused gating (fp32-exact) + x -> bf16 conversion ----------
__global__ void gate_convert(const float* __restrict__ x, const float* __restrict__ gw,
                             const float* __restrict__ gb, int* __restrict__ counts,
                             int* __restrict__ tlist, unsigned short* __restrict__ xbf) {
  const int lane = threadIdx.x & 63;
  const int tok  = blockIdx.x * 4 + (threadIdx.x >> 6);
  const float* xr = x + (size_t)tok * DIN;
  unsigned short* xo = xbf + (size_t)tok * DIN;
  float acc[NE];
  #pragma unroll
  for (int e = 0; e < NE; ++e) acc[e] = 0.f;
  for (int i = lane * 4; i < DIN; i += 256) {
    f32x4 xv = *(const f32x4*)(xr + i);
    *(unsigned long long*)(xo + i) = pack4(xv);
    #pragma unroll
    for (int e = 0; e < NE; ++e) {
      f32x4 wv = *(const f32x4*)(gw + e * DIN + i);
      acc[e] += xv[0]*wv[0] + xv[1]*wv[1] + xv[2]*wv[2] + xv[3]*wv[3];
    }
  }
  #pragma unroll
  for (int e = 0; e < NE; ++e) {
    float v = acc[e];
    #pragma unroll
    for (int o = 32; o > 0; o >>= 1) v += __shfl_xor(v, o);
    acc[e] = v;
  }
  if (lane == 0) {
    float bv = acc[0] + gb[0];
    int best = 0;
    #pragma unroll
    for (int e = 1; e < NE; ++e) {
      float v = acc[e] + gb[e];
      if (v > bv) { bv = v; best = e; }   // strict > == numpy first-max
    }
    int pos = atomicAdd(&counts[best], 1);
    tlist[best * TOK + pos] = tok;
  }
}

// ---------- expert weights fp32 -> bf16 ----------
__global__ void convw(const float* __restrict__ w, unsigned short* __restrict__ wbf) {
  const size_t n = (size_t)NE * DOUT * DIN;
  size_t idx = ((size_t)blockIdx.x * 256 + threadIdx.x) * 8;
  const size_t stride = (size_t)gridDim.x * 256 * 8;
  for (; idx < n; idx += stride) {
    f32x4 a = *(const f32x4*)(w + idx);
    f32x4 b = *(const f32x4*)(w + idx + 4);
    u64x2 v; v[0] = pack4(a); v[1] = pack4(b);
    *(u64x2*)(wbf + idx) = v;
  }
}

// ---------- fast grouped GEMM: 256x256 tile, ring-3 LDS, counted vmcnt ----------
__global__ __launch_bounds__(512, 2)
void moe_gemm_bf(const unsigned short* __restrict__ xbf,
                 const unsigned short* __restrict__ wbf,
                 const float* __restrict__ eb,
                 const int* __restrict__ counts,
                 const int* __restrict__ tlist,
                 float* __restrict__ out) {
  __shared__ unsigned short sA[3 * TSZ];   // 48 KB
  __shared__ unsigned short sB[3 * TSZ];   // 48 KB
  __shared__ int rowtok[BM];

  const int tid = threadIdx.x;

  // XCD-bijective swizzle of flattened grid (nwg = 640 = 8 XCD * 80)
  const int cpx  = gridDim.x >> 3;
  const int wgid = (blockIdx.x & 7) * cpx + (blockIdx.x >> 3);
  const int ntile = wgid & 15;     // slot-major: 16 n-tiles of one slot share an XCD's L2 (A-panel reuse)
  const int slot  = wgid >> 4;

  int e = -1, mtile = 0, Me = 0;
  {
    int acc = 0;
    #pragma unroll
    for (int j = 0; j < NE; ++j) {
      int c = counts[j];
      int t = (c + BM - 1) / BM;
      if (e < 0 && slot < acc + t) { e = j; mtile = slot - acc; Me = c; }
      acc += t;
    }
  }
  if (e < 0) return;

  const int n0 = ntile * BN;
  const int m0 = mtile * BM;
  const unsigned short* wbase = wbf + (size_t)e * DOUT * DIN;

  if (tid < BM) {
    int r = m0 + tid;
    rowtok[tid] = tlist[e * TOK + (r < Me ? r : Me - 1)];
  }
  __syncthreads();

  const int w = tid >> 6;   // wave 0..7
  const int l = tid & 63;

  // staging: per K-step each thread issues 2 A + 2 B gload16 (1 KB/wave/instr, linear dest)
  const int sr0 = w * 32 + (l >> 2);
  const int sr1 = sr0 + 16;
  const int c0 = ((l & 3) ^ ((sr0 >> 1) & 3)) * 8;  // pre-swizzled global chunk (T2 involution)
  const int c1 = ((l & 3) ^ ((sr1 >> 1) & 3)) * 8;
  const unsigned short* ga0 = xbf   + (size_t)rowtok[sr0] * DIN + c0;
  const unsigned short* ga1 = xbf   + (size_t)rowtok[sr1] * DIN + c1;
  const unsigned short* gb0 = wbase + (size_t)(n0 + sr0)  * DIN + c0;
  const unsigned short* gb1 = wbase + (size_t)(n0 + sr1)  * DIN + c1;
  const int la0 = (w * 32) * BK;        // wave-uniform LDS block bases
  const int la1 = (w * 32 + 16) * BK;

  // ds_read fragment offsets (swizzled)
  const int wm = w >> 2, wn = w & 3;
  const int lr = l & 15, lk = l >> 4;
  int offA[8], offB[4];
  #pragma unroll
  for (int m = 0; m < 8; ++m) {
    int r = wm * 128 + m * 16 + lr;
    offA[m] = r * BK + ((lk ^ ((r >> 1) & 3)) * 8);
  }
  #pragma unroll
  for (int n = 0; n < 4; ++n) {
    int r = wn * 64 + n * 16 + lr;
    offB[n] = r * BK + ((lk ^ ((r >> 1) & 3)) * 8);
  }

  f32x4 acc[8][4];
  #pragma unroll
  for (int m = 0; m < 8; ++m)
    #pragma unroll
    for (int n = 0; n < 4; ++n) acc[m][n] = (f32x4){0.f, 0.f, 0.f, 0.f};

#define STAGE(kt, b) do {                                                                   \
    const int ko_ = (kt) * BK;                                                              \
    const int bo_ = (b) * TSZ;                                                              \
    __builtin_amdgcn_global_load_lds((const AS1 unsigned int*)(ga0 + ko_),                  \
                                     (AS3 unsigned int*)&sA[bo_ + la0], 16, 0, 0);          \
    __builtin_amdgcn_global_load_lds((const AS1 unsigned int*)(ga1 + ko_),                  \
                                     (AS3 unsigned int*)&sA[bo_ + la1], 16, 0, 0);          \
    __builtin_amdgcn_global_load_lds((const AS1 unsigned int*)(gb0 + ko_),                  \
                                     (AS3 unsigned int*)&sB[bo_ + la0], 16, 0, 0);          \
    __builtin_amdgcn_global_load_lds((const AS1 unsigned int*)(gb1 + ko_),                  \
                                     (AS3 unsigned int*)&sB[bo_ + la1], 16, 0, 0);          \
  } while (0)

#define COMPUTE(b) do {                                                                     \
    const int bo_ = (b) * TSZ;                                                              \
    bf16x8 bv[4], av[4];                                                                    \
    _Pragma("unroll") for (int n = 0; n < 4; ++n)                                           \
      bv[n] = *(const bf16x8*)&sB[bo_ + offB[n]];                                           \
    _Pragma("unroll") for (int m = 0; m < 4; ++m)                                           \
      av[m] = *(const bf16x8*)&sA[bo_ + offA[m]];                                           \
    __builtin_amdgcn_s_setprio(1);                                                          \
    _Pragma("unroll") for (int m = 0; m < 4; ++m)                                           \
      _Pragma("unroll") for (int n = 0; n < 4; ++n)                                         \
        acc[m][n] = __builtin_amdgcn_mfma_f32_16x16x32_bf16(av[m], bv[n], acc[m][n], 0,0,0);\
    __builtin_amdgcn_s_setprio(0);                                                          \
    _Pragma("unroll") for (int m = 0; m < 4; ++m)                                           \
      av[m] = *(const bf16x8*)&sA[bo_ + offA[m + 4]];                                       \
    __builtin_amdgcn_s_setprio(1);                                                          \
    _Pragma("unroll") for (int m = 0; m < 4; ++m)                                           \
      _Pragma("unroll") for (int n = 0; n < 4; ++n)                                         \
        acc[m+4][n] = __builtin_amdgcn_mfma_f32_16x16x32_bf16(av[m], bv[n], acc[m+4][n], 0,0,0);\
    __builtin_amdgcn_s_setprio(0);                                                          \
  } while (0)

  // prologue: tiles 0,1 in flight; wait tile 0 landed (vmcnt counts 4 loads/tile)
  STAGE(0, 0);
  STAGE(1, 1);
  asm volatile("s_waitcnt vmcnt(4)" ::: "memory");
  __builtin_amdgcn_s_barrier();
  asm volatile("" ::: "memory");

  int ct = 0;
  for (int t = 0; t < NT - 2; ++t) {
    int bn = ct + 2; if (bn >= 3) bn -= 3;   // buffer freed at step t-1 (behind barrier)
    STAGE(t + 2, bn);
    COMPUTE(ct);
    asm volatile("s_waitcnt vmcnt(4)" ::: "memory");  // tile t+1 landed; t+2 stays in flight
    __builtin_amdgcn_s_barrier();
    asm volatile("" ::: "memory");
    ct = (ct == 2) ? 0 : ct + 1;
  }
  COMPUTE(ct);
  asm volatile("s_waitcnt vmcnt(0)" ::: "memory");
  __builtin_amdgcn_s_barrier();
  asm volatile("" ::: "memory");
  ct = (ct == 2) ? 0 : ct + 1;
  COMPUTE(ct);

  // epilogue: bias + guarded scatter (C/D: col = lane&15, row = (lane>>4)*4 + j)
  float bias[4];
  #pragma unroll
  for (int n = 0; n < 4; ++n) bias[n] = eb[e * DOUT + n0 + wn * 64 + n * 16 + lr];

  #pragma unroll
  for (int m = 0; m < 8; ++m) {
    #pragma unroll
    for (int j = 0; j < 4; ++j) {
      int rloc = wm * 128 + m * 16 + lk * 4 + j;
      if (m0 + rloc < Me) {
        int tokr = rowtok[rloc];
        float* op = out + (size_t)tokr * DOUT + n0 + wn * 64;
        #pragma unroll
        for (int n = 0; n < 4; ++n)
          op[n * 16 + lr] = acc[m][n][j] + bias[n];
      }
    }
  }
#undef STAGE
#undef COMPUTE
}

// ================= legacy fallback (fp32 direct, used only if ws too small) ==========
__global__ void gate_kernel(const float* __restrict__ x, const float* __restrict__ gw,
                            const float* __restrict__ gb, int* __restrict__ counts,
                            int* __restrict__ tlist) {
  const int lane = threadIdx.x & 63;
  const int tok  = blockIdx.x * 4 + (threadIdx.x >> 6);
  const float* xr = x + (size_t)tok * DIN;
  float acc[NE];
  #pragma unroll
  for (int e = 0; e < NE; ++e) acc[e] = 0.f;
  for (int i = lane; i < DIN; i += 64) {
    float xv = xr[i];
    #pragma unroll
    for (int e = 0; e < NE; ++e) acc[e] += xv * gw[e * DIN + i];
  }
  #pragma unroll
  for (int e = 0; e < NE; ++e) {
    float v = acc[e];
    #pragma unroll
    for (int o = 32; o > 0; o >>= 1) v += __shfl_xor(v, o);
    acc[e] = v;
  }
  if (lane == 0) {
    float bv = acc[0] + gb[0];
    int best = 0;
    #pragma unroll
    for (int e = 1; e < NE; ++e) {
      float v = acc[e] + gb[e];
      if (v > bv) { bv = v; best = e; }
    }
    int pos = atomicAdd(&counts[best], 1);
    tlist[best * TOK + pos] = tok;
  }
}

__global__ __launch_bounds__(256, 2)
void moe_gemm(const float* __restrict__ x, const float* __restrict__ ew,
              const float* __restrict__ eb, const int* __restrict__ counts,
              const int* __restrict__ tlist, float* __restrict__ out) {
  __shared__ unsigned short fA[2][FBM * LDSK];
  __shared__ unsigned short fB[2][FBM * LDSK];
  __shared__ int rowtok[FBM];

  const int tid  = threadIdx.x;
  const int slot = blockIdx.y;

  int e = -1, mtile = 0, Me = 0;
  {
    int acc = 0;
    #pragma unroll
    for (int j = 0; j < NE; ++j) {
      int c = counts[j];
      int t = (c + FBM - 1) / FBM;
      if (e < 0 && slot < acc + t) { e = j; mtile = slot - acc; Me = c; }
      acc += t;
    }
  }
  if (e < 0) return;

  const int n0 = blockIdx.x * FBM;
  const int m0 = mtile * FBM;
  const float* we = ew + (size_t)e * DOUT * DIN;

  if (tid < FBM) {
    int r = m0 + tid;
    rowtok[tid] = tlist[e * TOK + (r < Me ? r : Me - 1)];
  }
  __syncthreads();

  const int srow = tid >> 3;
  const int scol = (tid & 7) * 4;
  const int lane = tid & 63;
  const int w  = tid >> 6;
  const int wr = (w >> 1) * 64;
  const int wc = (w & 1) * 64;
  const int lr = lane & 15;
  const int lk = lane >> 4;

  f32x4 accf[4][4];
  #pragma unroll
  for (int m = 0; m < 4; ++m)
    #pragma unroll
    for (int n = 0; n < 4; ++n) accf[m][n] = (f32x4){0.f, 0.f, 0.f, 0.f};

  const float* aptr[4];
  const float* bptr[4];
  #pragma unroll
  for (int p = 0; p < 4; ++p) {
    int r = p * 32 + srow;
    aptr[p] = x  + (size_t)rowtok[r] * DIN + scol;
    bptr[p] = we + (size_t)(n0 + r)  * DIN + scol;
  }

  #pragma unroll
  for (int p = 0; p < 4; ++p) {
    int r = p * 32 + srow;
    *(unsigned long long*)&fA[0][r * LDSK + scol] = pack4(*(const f32x4*)(aptr[p]));
    *(unsigned long long*)&fB[0][r * LDSK + scol] = pack4(*(const f32x4*)(bptr[p]));
  }
  __syncthreads();

  int cur = 0;
  for (int kt = 0; kt < DIN / FBK; ++kt) {
    f32x4 ra[4], rb[4];
    const bool more = (kt + 1 < DIN / FBK);
    if (more) {
      const int koff = (kt + 1) * FBK;
      #pragma unroll
      for (int p = 0; p < 4; ++p) {
        ra[p] = *(const f32x4*)(aptr[p] + koff);
        rb[p] = *(const f32x4*)(bptr[p] + koff);
      }
    }
    bf16x8 af[4], bfr[4];
    #pragma unroll
    for (int m = 0; m < 4; ++m)
      af[m] = *(const bf16x8*)&fA[cur][(wr + m * 16 + lr) * LDSK + lk * 8];
    #pragma unroll
    for (int n = 0; n < 4; ++n)
      bfr[n] = *(const bf16x8*)&fB[cur][(wc + n * 16 + lr) * LDSK + lk * 8];
    #pragma unroll
    for (int m = 0; m < 4; ++m)
      #pragma unroll
      for (int n = 0; n < 4; ++n)
        accf[m][n] = __builtin_amdgcn_mfma_f32_16x16x32_bf16(af[m], bfr[n], accf[m][n], 0, 0, 0);
    if (more) {
      #pragma unroll
      for (int p = 0; p < 4; ++p) {
        int r = p * 32 + srow;
        *(unsigned long long*)&fA[cur ^ 1][r * LDSK + scol] = pack4(ra[p]);
        *(unsigned long long*)&fB[cur ^ 1][r * LDSK + scol] = pack4(rb[p]);
      }
    }
    __syncthreads();
    cur ^= 1;
  }

  float bias[4];
  #pragma unroll
  for (int n = 0; n < 4; ++n) bias[n] = eb[e * DOUT + n0 + wc + n * 16 + lr];

  #pragma unroll
  for (int m = 0; m < 4; ++m) {
    #pragma unroll
    for (int j = 0; j < 4; ++j) {
      int rloc = wr + m * 16 + lk * 4 + j;
      if (m0 + rloc < Me) {
        int tokr = rowtok[rloc];
        float* op = out + (size_t)tokr * DOUT + n0 + wc;
        #pragma unroll
        for (int n = 0; n < 4; ++n)
          op[n * 16 + lr] = accf[m][n][j] + bias[n];
      }
    }
  }
}

extern "C" void kernel_launch(void* const* d_in, const int* in_sizes, int n_in,
                              void* d_out, int out_size, void* d_ws, size_t ws_size,
                              hipStream_t stream) {
  const float* x  = (const float*)d_in[0];
  const float* gw = (const float*)d_in[1];
  const float* gb = (const float*)d_in[2];
  const float* ew = (const float*)d_in[3];
  const float* eb = (const float*)d_in[4];
  float* out = (float*)d_out;

  // ws layout: counts[16] | tlist[8*8192] | @1MB xbf (64MB) | wbf (256MB)
  int* counts = (int*)d_ws;
  int* tlist  = counts + 16;
  const size_t XOFF = 1u << 20;
  const size_t WOFF = XOFF + (size_t)TOK * DIN * 2;
  const size_t NEED = WOFF + (size_t)NE * DOUT * DIN * 2;

  hipMemsetAsync(counts, 0, 16 * sizeof(int), stream);

  if (ws_size >= NEED) {
    unsigned short* xbf = (unsigned short*)((char*)d_ws + XOFF);
    unsigned short* wbf = (unsigned short*)((char*)d_ws + WOFF);
    gate_convert<<<TOK / 4, 256, 0, stream>>>(x, gw, gb, counts, tlist, xbf);
    convw<<<8192, 256, 0, stream>>>(ew, wbf);
    // grid: 16 n-tiles x (TOK/256 + NE) worst-case slots = 640 blocks (divisible by 8 XCDs)
    moe_gemm_bf<<<16 * (TOK / BM + NE), 512, 0, stream>>>(xbf, wbf, eb, counts, tlist, out);
  } else {
    gate_kernel<<<TOK / 4, 256, 0, stream>>>(x, gw, gb, counts, tlist);
    dim3 grid(DOUT / FBM, TOK / FBM + NE, 1);
    moe_gemm<<<grid, 256, 0, stream>>>(x, ew, eb, counts, tlist, out);
  }
}

// Round 4
// 807.931 us; speedup vs baseline: 1.0343x; 1.0343x over previous
//
#include <hip/hip_runtime.h>

#define NE   8
#define DIN  4096
#define DOUT 4096
#define TOK  8192

// fast-path tile (m201-style 4-phase dbuf)
#define BM 256
#define BN 256
#define BK 64
#define NT (DIN / BK)      // 64 K-tiles
#define TSZ (BM * BK)      // 16384 bf16 elems per operand per buffer

// legacy fallback tile
#define FBM 128
#define FBK 32
#define LDSK 40

typedef __attribute__((ext_vector_type(4))) float f32x4;
typedef __attribute__((ext_vector_type(8))) short bf16x8;
typedef __attribute__((ext_vector_type(2))) unsigned long long u64x2;

#define AS1 __attribute__((address_space(1)))
#define AS3 __attribute__((address_space(3)))

static __device__ __forceinline__ unsigned short f2bf(float f) {
  unsigned u = __builtin_bit_cast(unsigned, f);
  u += 0x7fffu + ((u >> 16) & 1u);   // RTNE
  return (unsigned short)(u >> 16);
}

static __device__ __forceinline__ unsigned long long pack4(f32x4 v) {
  return (unsigned long long)f2bf(v[0])
       | ((unsigned long long)f2bf(v[1]) << 16)
       | ((unsigned long long)f2bf(v[2]) << 32)
       | ((unsigned long long)f2bf(v[3]) << 48);
}

static __device__ __forceinline__ void gload16(const void* g, void* l) {
  __builtin_amdgcn_global_load_lds((const AS1 unsigned int*)g,
                                   (AS3 unsigned int*)l, 16, 0, 0);
}

// ---------- fused gating (fp32-exact) + x -> bf16 conversion ----------
__global__ void gate_convert(const float* __restrict__ x, const float* __restrict__ gw,
                             const float* __restrict__ gb, int* __restrict__ counts,
                             int* __restrict__ tlist, unsigned short* __restrict__ xbf) {
  const int lane = threadIdx.x & 63;
  const int tok  = blockIdx.x * 4 + (threadIdx.x >> 6);
  const float* xr = x + (size_t)tok * DIN;
  unsigned short* xo = xbf + (size_t)tok * DIN;
  float acc[NE];
  #pragma unroll
  for (int e = 0; e < NE; ++e) acc[e] = 0.f;
  for (int i = lane * 4; i < DIN; i += 256) {
    f32x4 xv = *(const f32x4*)(xr + i);
    *(unsigned long long*)(xo + i) = pack4(xv);
    #pragma unroll
    for (int e = 0; e < NE; ++e) {
      f32x4 wv = *(const f32x4*)(gw + e * DIN + i);
      acc[e] += xv[0]*wv[0] + xv[1]*wv[1] + xv[2]*wv[2] + xv[3]*wv[3];
    }
  }
  #pragma unroll
  for (int e = 0; e < NE; ++e) {
    float v = acc[e];
    #pragma unroll
    for (int o = 32; o > 0; o >>= 1) v += __shfl_xor(v, o);
    acc[e] = v;
  }
  if (lane == 0) {
    float bv = acc[0] + gb[0];
    int best = 0;
    #pragma unroll
    for (int e = 1; e < NE; ++e) {
      float v = acc[e] + gb[e];
      if (v > bv) { bv = v; best = e; }   // strict > == numpy first-max
    }
    int pos = atomicAdd(&counts[best], 1);
    tlist[best * TOK + pos] = tok;
  }
}

// ---------- expert weights fp32 -> bf16 ----------
__global__ void convw(const float* __restrict__ w, unsigned short* __restrict__ wbf) {
  const size_t n = (size_t)NE * DOUT * DIN;
  size_t idx = ((size_t)blockIdx.x * 256 + threadIdx.x) * 8;
  const size_t stride = (size_t)gridDim.x * 256 * 8;
  for (; idx < n; idx += stride) {
    f32x4 a = *(const f32x4*)(w + idx);
    f32x4 b = *(const f32x4*)(w + idx + 4);
    u64x2 v; v[0] = pack4(a); v[1] = pack4(b);
    *(u64x2*)(wbf + idx) = v;
  }
}

// ---------- fast grouped GEMM: 256x256, BK=64, dbuf, 4-phase counted-vmcnt ----------
__global__ __launch_bounds__(512, 2)
void moe_gemm_bf(const unsigned short* __restrict__ xbf,
                 const unsigned short* __restrict__ wbf,
                 const float* __restrict__ eb,
                 const int* __restrict__ counts,
                 const int* __restrict__ tlist,
                 float* __restrict__ out) {
  __shared__ unsigned short sA[2][TSZ];   // 64 KB
  __shared__ unsigned short sB[2][TSZ];   // 64 KB
  __shared__ int rowtok[BM];

  const int tid = threadIdx.x;

  // XCD-bijective swizzle (nwg = 640 = 8 * 80); slot-major: one slot's 16
  // n-tiles land on one XCD -> A-panel L2 reuse
  const int cpx  = gridDim.x >> 3;
  const int wgid = (blockIdx.x & 7) * cpx + (blockIdx.x >> 3);
  const int ntile = wgid & 15;
  const int slot  = wgid >> 4;

  int e = -1, mtile = 0, Me = 0;
  {
    int accn = 0;
    #pragma unroll
    for (int j = 0; j < NE; ++j) {
      int c = counts[j];
      int tt = (c + BM - 1) / BM;
      if (e < 0 && slot < accn + tt) { e = j; mtile = slot - accn; Me = c; }
      accn += tt;
    }
  }
  if (e < 0) return;

  const int n0 = ntile * BN;
  const int m0 = mtile * BM;
  const unsigned short* wbase = wbf + (size_t)e * DOUT * DIN;

  if (tid < BM) {
    int r = m0 + tid;
    rowtok[tid] = tlist[e * TOK + (r < Me ? r : Me - 1)];
  }
  __syncthreads();

  const int w = tid >> 6, l = tid & 63;

  // staging: chunk = 64 rows x 64 cols (8 KB); thread -> (row srow, 16B slot sj)
  // source col pre-swizzled by involution f(row)=row&7 (= srow&7 for all chunks)
  const int srow = tid >> 3, sj = tid & 7;
  const int colsw = (sj ^ (srow & 7)) * 8;

  const unsigned short* ga[4];
  const unsigned short* gbp[4];
  #pragma unroll
  for (int c = 0; c < 4; ++c) {
    ga[c]  = xbf   + (size_t)rowtok[c * 64 + srow] * DIN + colsw;
    gbp[c] = wbase + (size_t)(n0 + c * 64 + srow)  * DIN + colsw;
  }
  const int ldsb = w * 512;   // wave base within an 8KB chunk (elems)

  // frag geometry: 8 waves as 2(M) x 4(N); per-wave 128x64 out
  const int wm = w >> 2, wn = w & 3;
  const int lr = l & 15, lk = l >> 4;
  const int s0 = (lk ^ (lr & 7)) * 8;          // kk0 slot (elems); kk1 = s0 ^ 32
  const int baseA = (wm * 128 + lr) * BK;
  const int baseB = (wn * 64  + lr) * BK;

  f32x4 acc[8][4];
  #pragma unroll
  for (int m = 0; m < 8; ++m)
    #pragma unroll
    for (int n = 0; n < 4; ++n) acc[m][n] = (f32x4){0.f, 0.f, 0.f, 0.f};

#define GLA(c, kt, q) gload16(ga[c]  + (size_t)(kt) * BK, &sA[q][(c) * 4096 + ldsb])
#define GLB(c, kt, q) gload16(gbp[c] + (size_t)(kt) * BK, &sB[q][(c) * 4096 + ldsb])
#define BARRIER() do { asm volatile("" ::: "memory");            \
                       __builtin_amdgcn_s_barrier();             \
                       asm volatile("" ::: "memory"); } while (0)

  // prologue: tile0 (8 chunks) -> buf0; tile1 chunks A0,A1 -> buf1
  GLA(0, 0, 0); GLA(1, 0, 0); GLA(2, 0, 0); GLA(3, 0, 0);
  GLB(0, 0, 0); GLB(1, 0, 0); GLB(2, 0, 0); GLB(3, 0, 0);
  GLA(0, 1, 1); GLA(1, 1, 1);
  asm volatile("s_waitcnt vmcnt(2)" ::: "memory");   // tile0 landed; 2 in flight
  BARRIER();

  for (int t = 0; t < NT; ++t) {
    const int q  = t & 1;
    const int t1 = (t + 1 < NT) ? t + 1 : t;   // clamped: data never read
    const int t2 = (t + 2 < NT) ? t + 2 : t;
    const unsigned short* Aq = sA[q];
    const unsigned short* Bq = sB[q];

    // B fragments for the whole K-tile (8 x b128), persistent in regs
    bf16x8 bv[4][2];
    #pragma unroll
    for (int n = 0; n < 4; ++n) {
      bv[n][0] = *(const bf16x8*)&Bq[baseB + n * 1024 + s0];
      bv[n][1] = *(const bf16x8*)&Bq[baseB + n * 1024 + (s0 ^ 32)];
    }

    #pragma unroll
    for (int ph = 0; ph < 4; ++ph) {
      bf16x8 a0k0 = *(const bf16x8*)&Aq[baseA + (ph * 2    ) * 1024 + s0];
      bf16x8 a0k1 = *(const bf16x8*)&Aq[baseA + (ph * 2    ) * 1024 + (s0 ^ 32)];
      bf16x8 a1k0 = *(const bf16x8*)&Aq[baseA + (ph * 2 + 1) * 1024 + s0];
      bf16x8 a1k1 = *(const bf16x8*)&Aq[baseA + (ph * 2 + 1) * 1024 + (s0 ^ 32)];
      // stage 2 chunks of tile t+1 into the non-read buffer
      if (ph == 0)      { GLA(2, t1, q ^ 1); GLA(3, t1, q ^ 1); }
      else if (ph == 1) { GLB(0, t1, q ^ 1); GLB(1, t1, q ^ 1); }
      else if (ph == 2) { GLB(2, t1, q ^ 1); GLB(3, t1, q ^ 1); }
      BARRIER();
      __builtin_amdgcn_s_setprio(1);
      #pragma unroll
      for (int n = 0; n < 4; ++n) {
        acc[ph*2  ][n] = __builtin_amdgcn_mfma_f32_16x16x32_bf16(a0k0, bv[n][0], acc[ph*2  ][n], 0, 0, 0);
        acc[ph*2  ][n] = __builtin_amdgcn_mfma_f32_16x16x32_bf16(a0k1, bv[n][1], acc[ph*2  ][n], 0, 0, 0);
        acc[ph*2+1][n] = __builtin_amdgcn_mfma_f32_16x16x32_bf16(a1k0, bv[n][0], acc[ph*2+1][n], 0, 0, 0);
        acc[ph*2+1][n] = __builtin_amdgcn_mfma_f32_16x16x32_bf16(a1k1, bv[n][1], acc[ph*2+1][n], 0, 0, 0);
      }
      __builtin_amdgcn_s_setprio(0);
      BARRIER();
    }
    // tail: buf q provably consumed by ALL waves (post-phase-3 barrier)
    GLA(0, t2, q); GLA(1, t2, q);
    asm volatile("s_waitcnt vmcnt(2)" ::: "memory");   // tile t+1 fully landed
    BARRIER();
  }

  // epilogue: bias + guarded scatter (C/D: col = lane&15, row = (lane>>4)*4 + j)
  float bias[4];
  #pragma unroll
  for (int n = 0; n < 4; ++n) bias[n] = eb[e * DOUT + n0 + wn * 64 + n * 16 + lr];

  #pragma unroll
  for (int m = 0; m < 8; ++m) {
    #pragma unroll
    for (int j = 0; j < 4; ++j) {
      int rloc = wm * 128 + m * 16 + lk * 4 + j;
      if (m0 + rloc < Me) {
        int tokr = rowtok[rloc];
        float* op = out + (size_t)tokr * DOUT + n0 + wn * 64;
        #pragma unroll
        for (int n = 0; n < 4; ++n)
          op[n * 16 + lr] = acc[m][n][j] + bias[n];
      }
    }
  }
#undef GLA
#undef GLB
#undef BARRIER
}

// ================= legacy fallback (fp32 direct, used only if ws too small) ==========
__global__ void gate_kernel(const float* __restrict__ x, const float* __restrict__ gw,
                            const float* __restrict__ gb, int* __restrict__ counts,
                            int* __restrict__ tlist) {
  const int lane = threadIdx.x & 63;
  const int tok  = blockIdx.x * 4 + (threadIdx.x >> 6);
  const float* xr = x + (size_t)tok * DIN;
  float acc[NE];
  #pragma unroll
  for (int e = 0; e < NE; ++e) acc[e] = 0.f;
  for (int i = lane; i < DIN; i += 64) {
    float xv = xr[i];
    #pragma unroll
    for (int e = 0; e < NE; ++e) acc[e] += xv * gw[e * DIN + i];
  }
  #pragma unroll
  for (int e = 0; e < NE; ++e) {
    float v = acc[e];
    #pragma unroll
    for (int o = 32; o > 0; o >>= 1) v += __shfl_xor(v, o);
    acc[e] = v;
  }
  if (lane == 0) {
    float bv = acc[0] + gb[0];
    int best = 0;
    #pragma unroll
    for (int e = 1; e < NE; ++e) {
      float v = acc[e] + gb[e];
      if (v > bv) { bv = v; best = e; }
    }
    int pos = atomicAdd(&counts[best], 1);
    tlist[best * TOK + pos] = tok;
  }
}

__global__ __launch_bounds__(256, 2)
void moe_gemm(const float* __restrict__ x, const float* __restrict__ ew,
              const float* __restrict__ eb, const int* __restrict__ counts,
              const int* __restrict__ tlist, float* __restrict__ out) {
  __shared__ unsigned short fA[2][FBM * LDSK];
  __shared__ unsigned short fB[2][FBM * LDSK];
  __shared__ int rowtok[FBM];

  const int tid  = threadIdx.x;
  const int slot = blockIdx.y;

  int e = -1, mtile = 0, Me = 0;
  {
    int acc = 0;
    #pragma unroll
    for (int j = 0; j < NE; ++j) {
      int c = counts[j];
      int t = (c + FBM - 1) / FBM;
      if (e < 0 && slot < acc + t) { e = j; mtile = slot - acc; Me = c; }
      acc += t;
    }
  }
  if (e < 0) return;

  const int n0 = blockIdx.x * FBM;
  const int m0 = mtile * FBM;
  const float* we = ew + (size_t)e * DOUT * DIN;

  if (tid < FBM) {
    int r = m0 + tid;
    rowtok[tid] = tlist[e * TOK + (r < Me ? r : Me - 1)];
  }
  __syncthreads();

  const int srow = tid >> 3;
  const int scol = (tid & 7) * 4;
  const int lane = tid & 63;
  const int w  = tid >> 6;
  const int wr = (w >> 1) * 64;
  const int wc = (w & 1) * 64;
  const int lr = lane & 15;
  const int lk = lane >> 4;

  f32x4 accf[4][4];
  #pragma unroll
  for (int m = 0; m < 4; ++m)
    #pragma unroll
    for (int n = 0; n < 4; ++n) accf[m][n] = (f32x4){0.f, 0.f, 0.f, 0.f};

  const float* aptr[4];
  const float* bptr[4];
  #pragma unroll
  for (int p = 0; p < 4; ++p) {
    int r = p * 32 + srow;
    aptr[p] = x  + (size_t)rowtok[r] * DIN + scol;
    bptr[p] = we + (size_t)(n0 + r)  * DIN + scol;
  }

  #pragma unroll
  for (int p = 0; p < 4; ++p) {
    int r = p * 32 + srow;
    *(unsigned long long*)&fA[0][r * LDSK + scol] = pack4(*(const f32x4*)(aptr[p]));
    *(unsigned long long*)&fB[0][r * LDSK + scol] = pack4(*(const f32x4*)(bptr[p]));
  }
  __syncthreads();

  int cur = 0;
  for (int kt = 0; kt < DIN / FBK; ++kt) {
    f32x4 ra[4], rb[4];
    const bool more = (kt + 1 < DIN / FBK);
    if (more) {
      const int koff = (kt + 1) * FBK;
      #pragma unroll
      for (int p = 0; p < 4; ++p) {
        ra[p] = *(const f32x4*)(aptr[p] + koff);
        rb[p] = *(const f32x4*)(bptr[p] + koff);
      }
    }
    bf16x8 af[4], bfr[4];
    #pragma unroll
    for (int m = 0; m < 4; ++m)
      af[m] = *(const bf16x8*)&fA[cur][(wr + m * 16 + lr) * LDSK + lk * 8];
    #pragma unroll
    for (int n = 0; n < 4; ++n)
      bfr[n] = *(const bf16x8*)&fB[cur][(wc + n * 16 + lr) * LDSK + lk * 8];
    #pragma unroll
    for (int m = 0; m < 4; ++m)
      #pragma unroll
      for (int n = 0; n < 4; ++n)
        accf[m][n] = __builtin_amdgcn_mfma_f32_16x16x32_bf16(af[m], bfr[n], accf[m][n], 0, 0, 0);
    if (more) {
      #pragma unroll
      for (int p = 0; p < 4; ++p) {
        int r = p * 32 + srow;
        *(unsigned long long*)&fA[cur ^ 1][r * LDSK + scol] = pack4(ra[p]);
        *(unsigned long long*)&fB[cur ^ 1][r * LDSK + scol] = pack4(rb[p]);
      }
    }
    __syncthreads();
    cur ^= 1;
  }

  float bias[4];
  #pragma unroll
  for (int n = 0; n < 4; ++n) bias[n] = eb[e * DOUT + n0 + wc + n * 16 + lr];

  #pragma unroll
  for (int m = 0; m < 4; ++m) {
    #pragma unroll
    for (int j = 0; j < 4; ++j) {
      int rloc = wr + m * 16 + lk * 4 + j;
      if (m0 + rloc < Me) {
        int tokr = rowtok[rloc];
        float* op = out + (size_t)tokr * DOUT + n0 + wc;
        #pragma unroll
        for (int n = 0; n < 4; ++n)
          op[n * 16 + lr] = accf[m][n][j] + bias[n];
      }
    }
  }
}

extern "C" void kernel_launch(void* const* d_in, const int* in_sizes, int n_in,
                              void* d_out, int out_size, void* d_ws, size_t ws_size,
                              hipStream_t stream) {
  const float* x  = (const float*)d_in[0];
  const float* gw = (const float*)d_in[1];
  const float* gb = (const float*)d_in[2];
  const float* ew = (const float*)d_in[3];
  const float* eb = (const float*)d_in[4];
  float* out = (float*)d_out;

  // ws layout: counts[16] | tlist[8*8192] | @1MB xbf (64MB) | wbf (256MB)
  int* counts = (int*)d_ws;
  int* tlist  = counts + 16;
  const size_t XOFF = 1u << 20;
  const size_t WOFF = XOFF + (size_t)TOK * DIN * 2;
  const size_t NEED = WOFF + (size_t)NE * DOUT * DIN * 2;

  hipMemsetAsync(counts, 0, 16 * sizeof(int), stream);

  if (ws_size >= NEED) {
    unsigned short* xbf = (unsigned short*)((char*)d_ws + XOFF);
    unsigned short* wbf = (unsigned short*)((char*)d_ws + WOFF);
    gate_convert<<<TOK / 4, 256, 0, stream>>>(x, gw, gb, counts, tlist, xbf);
    convw<<<8192, 256, 0, stream>>>(ew, wbf);
    // 16 n-tiles x (TOK/256 + NE) worst-case slots = 640 blocks (8 | 640)
    moe_gemm_bf<<<16 * (TOK / BM + NE), 512, 0, stream>>>(xbf, wbf, eb, counts, tlist, out);
  } else {
    gate_kernel<<<TOK / 4, 256, 0, stream>>>(x, gw, gb, counts, tlist);
    dim3 grid(DOUT / FBM, TOK / FBM + NE, 1);
    moe_gemm<<<grid, 256, 0, stream>>>(x, ew, eb, counts, tlist, out);
  }
}